// Round 22
// baseline (318.997 us; speedup 1.0000x reference)
//
#include <hip/hip_runtime.h>
#include <hip/hip_bf16.h>

// Max-tree (component tree) per channel, 64x64x3. Outputs (float32):
// parents [3,4096] then altitudes [3,4096].
//
// ranks = stable descending sort position (distinct, 0 = highest f) act as
// altitudes; rank-image max-tree's uncompressed pixel-parent == reference's
// (validated r2-r21). Distinct ranks => UNIQUE tree => order-independent
// incremental edge insertion via concurrent CAS splice-walks (r5-r21).
//
// r22 = EXACT r17 (best measured: 147.6us; r21 proved assemble time is
// boundary-count-invariant -> deep-zipper floor) + CONCURRENT HINT
// MATURATION on the idle wave (tid>=960) during the walk phase:
//  unguarded pointer-doubling skipw[n] := skipw[skipw[n]] (+ seed from
//  parw) — ALWAYS safe (ancestor-of-ancestor; the rank<=ry guard applies
//  at USE time). No barriers (r7 lesson), no extra per-step load (r18
//  lesson): walk code is r17-byte-identical; hints just mature underneath.
//  Fixed 24 batched passes (8-node MLP groups), then exit to barrier.
//
// Safety (r5-r21, schedule/subset/interleaving-agnostic): parw CAS is
// ABA-safe (non-root parent-rank strictly decreases; self word never
// recurs); climb on stale parent safe (splices only INSERT between x and
// parent); skipw slots always hold (rank(t)<<12)|t with t ancestor-or-self
// (helper writes preserve this; 32-bit stores word-atomic); jump guarded by
// rank<=ry (ranks strictly ascend along root paths; distinct ranks =>
// rank==ry <=> node==y). State stride 8B (16 banks) — never 16B (r11).
// Canon closed form g[p] = climb-from-parent-while-f-equal (validated r2-r21).

#define N_PIX 4096
#define CH 3

// ---------------------------------------------------------------------------
// K1a: blocked stable rank. 768 blocks = (c, si, sj), 256 threads.
// rank(p) = #{f[q]>f[p]} + #{f[q]==f[p], q<p}, accumulated by atomicAdd.
// ---------------------------------------------------------------------------
__global__ __launch_bounds__(256) void ct_rank(const float* __restrict__ vw,
                                               int* __restrict__ rank_g) {
    __shared__ __align__(16) float seg[256];
    const int b   = blockIdx.x;
    const int c   = b >> 8;
    const int si  = (b >> 4) & 15;
    const int sj  = b & 15;
    const int tid = threadIdx.x;

    seg[tid] = vw[((sj << 8) + tid) * CH + c];
    __syncthreads();

    const int   p  = (si << 8) + tid;
    const float vp = vw[p * CH + c];
    const int jbase = sj << 8;
    int cnt = 0;
    const float4* v4 = reinterpret_cast<const float4*>(seg);
#pragma unroll 8
    for (int j4 = 0; j4 < 64; ++j4) {
        float4 q = v4[j4];
        int j = jbase + (j4 << 2);
        cnt += (q.x > vp) || ((q.x == vp) && (j     < p));
        cnt += (q.y > vp) || ((q.y == vp) && (j + 1 < p));
        cnt += (q.z > vp) || ((q.z == vp) && (j + 2 < p));
        cnt += (q.w > vp) || ((q.w == vp) && (j + 3 < p));
    }
    atomicAdd(&rank_g[(c << 12) + p], cnt);
}

// ---------------------------------------------------------------------------
// K1b: intra-strip concurrent build. 48 blocks x 256 threads (r17 verbatim).
// ---------------------------------------------------------------------------
__global__ __launch_bounds__(256) void ct_build(const int* __restrict__ rank_g,
                                                unsigned* __restrict__ word_g) {
    __shared__ unsigned short rankS[256];
    __shared__ __align__(8) unsigned st[2 * 256];        // 2 KB (parw,skipw)
    const int c    = blockIdx.x >> 4;
    const int seg  = blockIdx.x & 15;
    const int tid  = threadIdx.x;
    const int base = seg << 8;
    const int p    = base + tid;

    const unsigned r = (unsigned)rank_g[(c << 12) + p];
    rankS[tid] = (unsigned short)r;
    const unsigned selfw = (r << 12) | (unsigned)p;      // global id
    st[2 * tid]     = selfw;                             // parw (root)
    st[2 * tid + 1] = selfw;                             // skipw (self)
    __syncthreads();

    // ---- insert 444 intra-strip edges (2 slots/thread), local indexing ----
    int xlA[2], pxA[2], x0A[2];
    unsigned ywA[2];
    unsigned act = 0;
#pragma unroll
    for (int k = 0; k < 2; ++k) {
        xlA[k] = 0; pxA[k] = -1; x0A[k] = 0; ywA[k] = 0;
        const int e = (k << 8) + tid;
        if (e < 444) {
            int xl, yl;
            if (e < 252) { const int lr = e / 63; xl = (lr << 6) + (e - lr * 63); yl = xl + 1; }
            else         { const int e2 = e - 252; xl = ((e2 >> 6) << 6) + (e2 & 63); yl = xl + 64; }
            unsigned rx = rankS[xl], ry = rankS[yl];
            if (rx > ry) { int t = xl; xl = yl; yl = t; unsigned tr = rx; rx = ry; ry = tr; }
            xlA[k]  = xl;
            x0A[k]  = xl;
            ywA[k]  = (ry << 12) | (unsigned)(base + yl);
            act    |= 1u << k;
        }
    }

    auto stepL = [&](int k, unsigned long long lv) {
        const int      xl = xlA[k];
        const unsigned xg = (unsigned)(base + xl);
        const unsigned yw = ywA[k];
        const unsigned ry = yw >> 12;
        const unsigned w  = (unsigned)lv;
        const unsigned sk = (unsigned)(lv >> 32);
        if (pxA[k] >= 0) { st[2 * pxA[k] + 1] = sk; pxA[k] = -1; }
        const unsigned s = sk & 0xFFFu;
        if (s != xg && (sk >> 12) <= ry) {                     // hint jump
            if (s == (yw & 0xFFFu)) { st[2 * x0A[k] + 1] = yw; act &= ~(1u << k); }
            else { pxA[k] = xl; xlA[k] = (int)(s & 255u); }
            return;
        }
        const unsigned pg = w & 0xFFFu, rp = w >> 12;
        if (pg == xg) {                                        // root: attach y
            if (atomicCAS(&st[2 * xl], w, yw) == w) {
                st[2 * xl + 1] = yw; st[2 * x0A[k] + 1] = yw;
                act &= ~(1u << k);
            }
        } else if (rp < ry) {                                  // climb
            if (s == xg) st[2 * xl + 1] = w;
            xlA[k] = (int)(pg & 255u);
        } else if (rp > ry) {                                  // splice
            if (atomicCAS(&st[2 * xl], w, yw) == w) {
                st[2 * xl + 1] = yw; st[2 * x0A[k] + 1] = yw;
                xlA[k] = (int)(yw & 255u); x0A[k] = xlA[k]; ywA[k] = w;
            }
        } else { st[2 * x0A[k] + 1] = yw; act &= ~(1u << k); } // p==y
    };

    while (act) {
        unsigned long long ld[2];
#pragma unroll
        for (int k = 0; k < 2; ++k)
            if (act & (1u << k))
                ld[k] = *((volatile unsigned long long*)&st[2 * xlA[k]]);
#pragma unroll
        for (int k = 0; k < 2; ++k)
            if (act & (1u << k)) stepL(k, ld[k]);
    }
    __syncthreads();

    word_g[2 * ((c << 12) + p)]     = st[2 * tid];
    word_g[2 * ((c << 12) + p) + 1] = st[2 * tid + 1];
}

// ---------------------------------------------------------------------------
// K2: cross-edge assembly (pipelined walks, wave=boundary) + concurrent
// hint-maturation helpers + canon + output. 3 blocks x 1024 threads.
// ---------------------------------------------------------------------------
__global__ __launch_bounds__(1024) void ct_assemble(const float* __restrict__ vw,
                                                    const int* __restrict__ rank_g,
                                                    const unsigned* __restrict__ word_g,
                                                    float* __restrict__ out) {
    __shared__ __align__(16) unsigned state[2 * N_PIX];  // 32 KB
    __shared__ float vals[N_PIX];                        // 16 KB
    const int c   = blockIdx.x;
    const int tid = threadIdx.x;

    for (int p = tid; p < N_PIX; p += 1024) {
        state[2 * p]     = word_g[2 * ((c << 12) + p)];
        state[2 * p + 1] = word_g[2 * ((c << 12) + p) + 1];
        vals[p]          = vw[p * CH + c];
    }
    __syncthreads();

    if (tid < 960) {
        // ---- walker: one cross edge; WAVE = BOUNDARY (b = tid>>6) ----
        const int b   = tid >> 6;               // boundary 0..14 (one wave each)
        const int col = tid & 63;
        int xg = (((b << 2) + 3) << 6) + col;   // row 4b+3
        int yg = xg + 64;                       // row 4b+4
        unsigned rx = (unsigned)rank_g[(c << 12) + xg];
        unsigned ry = (unsigned)rank_g[(c << 12) + yg];
        if (rx > ry) { int t = xg; xg = yg; yg = t; unsigned tr = rx; rx = ry; ry = tr; }

        int x = xg, x0 = xg, px = -1;
        unsigned yw = (ry << 12) | (unsigned)yg;
        volatile unsigned long long* vst = (volatile unsigned long long*)state;
        unsigned long long lv = vst[x];
        bool on = true;
        while (on) {
            const unsigned w   = (unsigned)lv;
            const unsigned sk  = (unsigned)(lv >> 32);
            const unsigned ryc = yw >> 12;
            const unsigned ylo = yw & 0xFFFu;
            const unsigned s   = sk & 0xFFFu;
            const unsigned p   = w & 0xFFFu;
            const unsigned rp  = w >> 12;

            const bool hjump = (s != (unsigned)x) && ((sk >> 12) <= ryc);
            const bool climb = !hjump && (p != (unsigned)x) && (rp < ryc);

            if (hjump | climb) {
                const int nx = (int)(hjump ? s : p);
                const bool term = hjump && (s == ylo);
                unsigned long long lvn = 0;
                if (!term) lvn = vst[nx];                    // issue early!
                // overlapped stores while lvn is in flight
                if (px >= 0) { state[2 * px + 1] = sk; px = -1; }
                if (term) { state[2 * x0 + 1] = yw; on = false; }
                else {
                    if (hjump) px = x;
                    else if (s == (unsigned)x) state[2 * x + 1] = w;  // memo
                    x = nx; lv = lvn;
                }
                continue;
            }

            // slow path: root attach / splice / p==y
            if (px >= 0) { state[2 * px + 1] = sk; px = -1; }
            if (p == (unsigned)x) {                          // root: attach y
                if (atomicCAS(&state[2 * x], w, yw) == w) {
                    state[2 * x + 1] = yw; state[2 * x0 + 1] = yw;
                    on = false;
                } else lv = vst[x];
            } else if (rp > ryc) {                           // splice
                if (atomicCAS(&state[2 * x], w, yw) == w) {
                    state[2 * x + 1] = yw; state[2 * x0 + 1] = yw;
                    x = (int)ylo; x0 = x; yw = w;
                }
                lv = vst[x];
            } else {                                         // rp==ryc => p==y
                state[2 * x0 + 1] = yw;
                on = false;
            }
        }
    } else {
        // ---- helper wave (64 lanes): concurrent hint maturation ----
        // skipw[n] := skipw[skipw[n]] (seed from parw) — unguarded doubling
        // is always ancestor-safe; usability is checked at jump time.
        const int base = (tid - 960) << 6;       // 64 nodes per lane
        volatile unsigned* vsk = (volatile unsigned*)state;
        for (int pass = 0; pass < 24; ++pass) {
            for (int g = 0; g < 8; ++g) {        // 8 groups of 8 (MLP batch)
                const int nb = base + (g << 3);
                unsigned skv[8];
#pragma unroll
                for (int i = 0; i < 8; ++i) skv[i] = vsk[2 * (nb + i) + 1];
                unsigned tgt[8];
#pragma unroll
                for (int i = 0; i < 8; ++i) {
                    const unsigned s = skv[i] & 0xFFFu;
                    // self-hint: seed from parent word; else double via hint
                    tgt[i] = (s == (unsigned)(nb + i)) ? (unsigned)(2 * s)
                                                       : (unsigned)(2 * s + 1);
                }
                unsigned nxt[8];
#pragma unroll
                for (int i = 0; i < 8; ++i) nxt[i] = vsk[tgt[i]];
#pragma unroll
                for (int i = 0; i < 8; ++i) {
                    const int n = nb + i;
                    const unsigned nw = nxt[i];
                    const unsigned t  = nw & 0xFFFu;
                    // write only a real advance (t must differ from n and
                    // from the slot it came from being self-stuck)
                    if (t != (unsigned)n && t != ((skv[i] & 0xFFFu)))
                        state[2 * n + 1] = nw;
                    else if ((skv[i] & 0xFFFu) == (unsigned)n && t != (unsigned)n)
                        state[2 * n + 1] = nw;   // seeded parent
                }
            }
        }
    }
    __syncthreads();

    // ---- canon (g[p] = climb-from-parent-while-f-equal) + output ----
    for (int p = tid; p < N_PIX; p += 1024) {
        int q = state[2 * p] & 0xFFF;
        const float fq = vals[q];
        for (;;) {
            const int qp = state[2 * q] & 0xFFF;
            if (qp == q) break;
            if (vals[qp] != fq) break;
            q = qp;
        }
        out[(c << 12) + p] = (float)q;
        out[CH * N_PIX + (c << 12) + p] = vals[p];
    }
}

extern "C" void kernel_launch(void* const* d_in, const int* in_sizes, int n_in,
                              void* d_out, int out_size, void* d_ws, size_t ws_size,
                              hipStream_t stream) {
    const float* vw = (const float*)d_in[0];
    float* out = (float*)d_out;

    int*      rank_g = (int*)d_ws;                        // 3*4096 ints
    unsigned* word_g = (unsigned*)(rank_g + CH * N_PIX);  // 2*3*4096 uints

    hipMemsetAsync(rank_g, 0, CH * N_PIX * sizeof(int), stream);
    ct_rank    <<<768, 256, 0, stream>>>(vw, rank_g);
    ct_build   <<<48, 256, 0, stream>>>(rank_g, word_g);
    ct_assemble<<<CH, 1024, 0, stream>>>(vw, rank_g, word_g, out);
}

// Round 23
// 162.554 us; speedup vs baseline: 1.9624x; 1.9624x over previous
//
#include <hip/hip_runtime.h>
#include <hip/hip_bf16.h>

// Max-tree (component tree) per channel, 64x64x3. Outputs (float32):
// parents [3,4096] then altitudes [3,4096].
//
// ranks = stable descending sort position (distinct, 0 = highest f) act as
// altitudes; rank-image max-tree's uncompressed pixel-parent == reference's
// (validated r2-r22). Distinct ranks => UNIQUE tree => order-independent
// incremental edge insertion via concurrent CAS splice-walks (r5-r22).
//
// r23 = assemble reverted to r17-EXACT (best measured 147.6us; r18/r21/r22
// all failed to beat the deep-zipper latency floor ~115us) + the non-
// assemble overhead squeezed:
//  - no memset, no atomics: ct_rank (192 blocks = c x 16si x 4g) writes
//    ushort PARTIAL counts overlaid into word_g's region ((c*16+seg)*512
//    uints; partial idx g*256+tid as ushort). Sole reader (ct_build block
//    (c,seg)) consumes them before overwriting the region with words —
//    same-block RAW separated by __syncthreads, zero extra workspace.
//  - ct_build sums 4 partials/pixel, stores rank to ushort rank_g2 (24KB)
//    for assemble's boundary lookups.
//  - 3 dispatches total (was 4).
//
// Safety (r5-r22, schedule/subset/interleaving-agnostic): parw CAS is
// ABA-safe (non-root parent-rank strictly decreases; self word never
// recurs); climb on stale parent safe (splices only INSERT between x and
// parent); skipw hints are ancestors-or-self, jump guarded by rank<=ry
// (ranks strictly ascend along root paths; distinct ranks => rank==ry <=>
// node==y); racy 32-bit hint stores word-atomic; speculative loads safe.
// State stride 8B (16 banks) — never 16B (r11 lesson).
// Canon closed form g[p] = climb-from-parent-while-f-equal (validated r2-r22).

#define N_PIX 4096
#define CH 3

// ---------------------------------------------------------------------------
// K1a: blocked stable rank -> ushort partials overlaid in word_g.
// 192 blocks = (c, si, g); block compares si's 256 pixels vs g's 1024 pixels.
// rank(p) = #{f[q]>f[p]} + #{f[q]==f[p], q<p}.
// ---------------------------------------------------------------------------
__global__ __launch_bounds__(256) void ct_rank(const float* __restrict__ vw,
                                               unsigned* __restrict__ word_g) {
    __shared__ __align__(16) float seg[1024];
    const int b   = blockIdx.x;
    const int c   = b >> 6;
    const int si  = (b >> 2) & 15;
    const int g   = b & 3;
    const int tid = threadIdx.x;
    const int jbase = g << 10;

    for (int i = tid; i < 1024; i += 256) seg[i] = vw[(jbase + i) * CH + c];
    __syncthreads();

    const int   p  = (si << 8) + tid;
    const float vp = vw[p * CH + c];
    int cnt = 0;
    const float4* v4 = reinterpret_cast<const float4*>(seg);
#pragma unroll 8
    for (int j4 = 0; j4 < 256; ++j4) {
        float4 q = v4[j4];
        int j = jbase + (j4 << 2);
        cnt += (q.x > vp) || ((q.x == vp) && (j     < p));
        cnt += (q.y > vp) || ((q.y == vp) && (j + 1 < p));
        cnt += (q.z > vp) || ((q.z == vp) && (j + 2 < p));
        cnt += (q.w > vp) || ((q.w == vp) && (j + 3 < p));
    }
    unsigned short* pu =
        (unsigned short*)(word_g + (((c << 4) | si) << 9));  // region base
    pu[(g << 8) + tid] = (unsigned short)cnt;
}

// ---------------------------------------------------------------------------
// K1b: intra-strip concurrent build. 48 blocks x 256 threads.
// Sums partials -> rank; builds strip tree (r17 walk verbatim); overwrites
// its word_g region with (parw,skipw); stores rank to rank_g2.
// ---------------------------------------------------------------------------
__global__ __launch_bounds__(256) void ct_build(unsigned* __restrict__ word_g,
                                                unsigned short* __restrict__ rank_g2) {
    __shared__ unsigned short rankS[256];
    __shared__ __align__(8) unsigned st[2 * 256];        // 2 KB (parw,skipw)
    const int c    = blockIdx.x >> 4;
    const int seg  = blockIdx.x & 15;
    const int tid  = threadIdx.x;
    const int base = seg << 8;
    const int p    = base + tid;

    const unsigned short* pu =
        (const unsigned short*)(word_g + (((c << 4) | seg) << 9));
    const unsigned r = (unsigned)pu[tid] + (unsigned)pu[256 + tid]
                     + (unsigned)pu[512 + tid] + (unsigned)pu[768 + tid];
    rankS[tid] = (unsigned short)r;
    rank_g2[(c << 12) + p] = (unsigned short)r;
    const unsigned selfw = (r << 12) | (unsigned)p;      // global id
    st[2 * tid]     = selfw;                             // parw (root)
    st[2 * tid + 1] = selfw;                             // skipw (self)
    __syncthreads();   // all partial reads done before any word write below

    // ---- insert 444 intra-strip edges (2 slots/thread), local indexing ----
    int xlA[2], pxA[2], x0A[2];
    unsigned ywA[2];
    unsigned act = 0;
#pragma unroll
    for (int k = 0; k < 2; ++k) {
        xlA[k] = 0; pxA[k] = -1; x0A[k] = 0; ywA[k] = 0;
        const int e = (k << 8) + tid;
        if (e < 444) {
            int xl, yl;
            if (e < 252) { const int lr = e / 63; xl = (lr << 6) + (e - lr * 63); yl = xl + 1; }
            else         { const int e2 = e - 252; xl = ((e2 >> 6) << 6) + (e2 & 63); yl = xl + 64; }
            unsigned rx = rankS[xl], ry = rankS[yl];
            if (rx > ry) { int t = xl; xl = yl; yl = t; unsigned tr = rx; rx = ry; ry = tr; }
            xlA[k]  = xl;
            x0A[k]  = xl;
            ywA[k]  = (ry << 12) | (unsigned)(base + yl);
            act    |= 1u << k;
        }
    }

    auto stepL = [&](int k, unsigned long long lv) {
        const int      xl = xlA[k];
        const unsigned xg = (unsigned)(base + xl);
        const unsigned yw = ywA[k];
        const unsigned ry = yw >> 12;
        const unsigned w  = (unsigned)lv;
        const unsigned sk = (unsigned)(lv >> 32);
        if (pxA[k] >= 0) { st[2 * pxA[k] + 1] = sk; pxA[k] = -1; }
        const unsigned s = sk & 0xFFFu;
        if (s != xg && (sk >> 12) <= ry) {                     // hint jump
            if (s == (yw & 0xFFFu)) { st[2 * x0A[k] + 1] = yw; act &= ~(1u << k); }
            else { pxA[k] = xl; xlA[k] = (int)(s & 255u); }
            return;
        }
        const unsigned pg = w & 0xFFFu, rp = w >> 12;
        if (pg == xg) {                                        // root: attach y
            if (atomicCAS(&st[2 * xl], w, yw) == w) {
                st[2 * xl + 1] = yw; st[2 * x0A[k] + 1] = yw;
                act &= ~(1u << k);
            }
        } else if (rp < ry) {                                  // climb
            if (s == xg) st[2 * xl + 1] = w;
            xlA[k] = (int)(pg & 255u);
        } else if (rp > ry) {                                  // splice
            if (atomicCAS(&st[2 * xl], w, yw) == w) {
                st[2 * xl + 1] = yw; st[2 * x0A[k] + 1] = yw;
                xlA[k] = (int)(yw & 255u); x0A[k] = xlA[k]; ywA[k] = w;
            }
        } else { st[2 * x0A[k] + 1] = yw; act &= ~(1u << k); } // p==y
    };

    while (act) {
        unsigned long long ld[2];
#pragma unroll
        for (int k = 0; k < 2; ++k)
            if (act & (1u << k))
                ld[k] = *((volatile unsigned long long*)&st[2 * xlA[k]]);
#pragma unroll
        for (int k = 0; k < 2; ++k)
            if (act & (1u << k)) stepL(k, ld[k]);
    }
    __syncthreads();

    // overwrite this block's region (partials already consumed)
    word_g[2 * ((c << 12) + p)]     = st[2 * tid];
    word_g[2 * ((c << 12) + p) + 1] = st[2 * tid + 1];
}

// ---------------------------------------------------------------------------
// K2: cross-edge assembly (r17-exact pipelined walks, wave=boundary)
// + canon + output. 3 blocks x 1024 threads.
// ---------------------------------------------------------------------------
__global__ __launch_bounds__(1024) void ct_assemble(const float* __restrict__ vw,
                                                    const unsigned short* __restrict__ rank_g2,
                                                    const unsigned* __restrict__ word_g,
                                                    float* __restrict__ out) {
    __shared__ __align__(16) unsigned state[2 * N_PIX];  // 32 KB
    __shared__ float vals[N_PIX];                        // 16 KB
    const int c   = blockIdx.x;
    const int tid = threadIdx.x;

    for (int p = tid; p < N_PIX; p += 1024) {
        state[2 * p]     = word_g[2 * ((c << 12) + p)];
        state[2 * p + 1] = word_g[2 * ((c << 12) + p) + 1];
        vals[p]          = vw[p * CH + c];
    }
    __syncthreads();

    // ---- one cross edge per thread; WAVE = BOUNDARY (b = tid>>6) ----
    if (tid < 960) {
        const int b   = tid >> 6;               // boundary 0..14 (one wave each)
        const int col = tid & 63;
        int xg = (((b << 2) + 3) << 6) + col;   // row 4b+3
        int yg = xg + 64;                       // row 4b+4
        unsigned rx = (unsigned)rank_g2[(c << 12) + xg];
        unsigned ry = (unsigned)rank_g2[(c << 12) + yg];
        if (rx > ry) { int t = xg; xg = yg; yg = t; unsigned tr = rx; rx = ry; ry = tr; }

        int x = xg, x0 = xg, px = -1;
        unsigned yw = (ry << 12) | (unsigned)yg;
        volatile unsigned long long* vst = (volatile unsigned long long*)state;
        unsigned long long lv = vst[x];
        bool on = true;
        while (on) {
            const unsigned w   = (unsigned)lv;
            const unsigned sk  = (unsigned)(lv >> 32);
            const unsigned ryc = yw >> 12;
            const unsigned ylo = yw & 0xFFFu;
            const unsigned s   = sk & 0xFFFu;
            const unsigned p   = w & 0xFFFu;
            const unsigned rp  = w >> 12;

            const bool hjump = (s != (unsigned)x) && ((sk >> 12) <= ryc);
            const bool climb = !hjump && (p != (unsigned)x) && (rp < ryc);

            if (hjump | climb) {
                const int nx = (int)(hjump ? s : p);
                const bool term = hjump && (s == ylo);
                unsigned long long lvn = 0;
                if (!term) lvn = vst[nx];                    // issue early!
                // overlapped stores while lvn is in flight
                if (px >= 0) { state[2 * px + 1] = sk; px = -1; }
                if (term) { state[2 * x0 + 1] = yw; on = false; }
                else {
                    if (hjump) px = x;
                    else if (s == (unsigned)x) state[2 * x + 1] = w;  // memo
                    x = nx; lv = lvn;
                }
                continue;
            }

            // slow path: root attach / splice / p==y
            if (px >= 0) { state[2 * px + 1] = sk; px = -1; }
            if (p == (unsigned)x) {                          // root: attach y
                if (atomicCAS(&state[2 * x], w, yw) == w) {
                    state[2 * x + 1] = yw; state[2 * x0 + 1] = yw;
                    on = false;
                } else lv = vst[x];
            } else if (rp > ryc) {                           // splice
                if (atomicCAS(&state[2 * x], w, yw) == w) {
                    state[2 * x + 1] = yw; state[2 * x0 + 1] = yw;
                    x = (int)ylo; x0 = x; yw = w;
                }
                lv = vst[x];
            } else {                                         // rp==ryc => p==y
                state[2 * x0 + 1] = yw;
                on = false;
            }
        }
    }
    __syncthreads();

    // ---- canon (g[p] = climb-from-parent-while-f-equal) + output ----
    for (int p = tid; p < N_PIX; p += 1024) {
        int q = state[2 * p] & 0xFFF;
        const float fq = vals[q];
        for (;;) {
            const int qp = state[2 * q] & 0xFFF;
            if (qp == q) break;
            if (vals[qp] != fq) break;
            q = qp;
        }
        out[(c << 12) + p] = (float)q;
        out[CH * N_PIX + (c << 12) + p] = vals[p];
    }
}

extern "C" void kernel_launch(void* const* d_in, const int* in_sizes, int n_in,
                              void* d_out, int out_size, void* d_ws, size_t ws_size,
                              hipStream_t stream) {
    const float* vw = (const float*)d_in[0];
    float* out = (float*)d_out;

    unsigned*       word_g  = (unsigned*)d_ws;                 // 2*3*4096 uints (98KB)
    unsigned short* rank_g2 = (unsigned short*)(word_g + 2 * CH * N_PIX);  // 24KB

    ct_rank    <<<192, 256, 0, stream>>>(vw, word_g);
    ct_build   <<<48, 256, 0, stream>>>(word_g, rank_g2);
    ct_assemble<<<CH, 1024, 0, stream>>>(vw, rank_g2, word_g, out);
}

// Round 24
// 149.956 us; speedup vs baseline: 2.1273x; 1.0840x over previous
//
#include <hip/hip_runtime.h>
#include <hip/hip_bf16.h>

// Max-tree (component tree) per channel, 64x64x3. Outputs (float32):
// parents [3,4096] then altitudes [3,4096].
//
// FINAL (r24) = r17 byte-identical — best measured configuration (147.6us).
// 23 rounds established:
//  - ranks = stable descending sort position (distinct) act as altitudes;
//    the rank-image max-tree's uncompressed pixel-parent == reference's
//    (union phase is purely order-driven). Distinct ranks => UNIQUE tree
//    => order-independent concurrent CAS splice-walk insertion.
//  - structure: 768-block blocked rank (atomicAdd partials), 48-block
//    intra-strip builds (2-slot MLP walks), 3-block cross-edge assembly
//    (wave=boundary, software-pipelined walks), closed-form canon.
//  - the assembly's ~115us is the splice-causality chain of the deep
//    zipper (~2000 causally-ordered LDS steps x ~140cy); seven distinct
//    restructurings (r14,r18,r19,r20,r21,r22,r23) were neutral/negative.
//    Occupancy 0.45%, VALUBusy 0.3%, HBM 0.03% — latency-bound, no HW
//    pipe saturated; the bound is algorithmic.
//
// Safety (validated r2-r23): parw CAS is ABA-safe (non-root parent-rank
// strictly decreases; self word never recurs); climb on stale parent safe
// (splices only INSERT between x and parent); skipw hints ancestor-or-self,
// jump guarded by rank<=ry (ranks strictly ascend along root paths;
// distinct ranks => rank==ry <=> node==y); racy 32-bit hint stores
// word-atomic; speculative next-load safe. State stride 8B (16 banks).
// Canon closed form g[p] = climb-from-parent-while-f-equal.

#define N_PIX 4096
#define CH 3

// ---------------------------------------------------------------------------
// K1a: blocked stable rank. 768 blocks = (c, si, sj), 256 threads.
// rank(p) = #{f[q]>f[p]} + #{f[q]==f[p], q<p}, accumulated by atomicAdd.
// ---------------------------------------------------------------------------
__global__ __launch_bounds__(256) void ct_rank(const float* __restrict__ vw,
                                               int* __restrict__ rank_g) {
    __shared__ __align__(16) float seg[256];
    const int b   = blockIdx.x;
    const int c   = b >> 8;
    const int si  = (b >> 4) & 15;
    const int sj  = b & 15;
    const int tid = threadIdx.x;

    seg[tid] = vw[((sj << 8) + tid) * CH + c];
    __syncthreads();

    const int   p  = (si << 8) + tid;
    const float vp = vw[p * CH + c];
    const int jbase = sj << 8;
    int cnt = 0;
    const float4* v4 = reinterpret_cast<const float4*>(seg);
#pragma unroll 8
    for (int j4 = 0; j4 < 64; ++j4) {
        float4 q = v4[j4];
        int j = jbase + (j4 << 2);
        cnt += (q.x > vp) || ((q.x == vp) && (j     < p));
        cnt += (q.y > vp) || ((q.y == vp) && (j + 1 < p));
        cnt += (q.z > vp) || ((q.z == vp) && (j + 2 < p));
        cnt += (q.w > vp) || ((q.w == vp) && (j + 3 < p));
    }
    atomicAdd(&rank_g[(c << 12) + p], cnt);
}

// ---------------------------------------------------------------------------
// K1b: intra-strip concurrent build. 48 blocks x 256 threads.
// ---------------------------------------------------------------------------
__global__ __launch_bounds__(256) void ct_build(const int* __restrict__ rank_g,
                                                unsigned* __restrict__ word_g) {
    __shared__ unsigned short rankS[256];
    __shared__ __align__(8) unsigned st[2 * 256];        // 2 KB (parw,skipw)
    const int c    = blockIdx.x >> 4;
    const int seg  = blockIdx.x & 15;
    const int tid  = threadIdx.x;
    const int base = seg << 8;
    const int p    = base + tid;

    const unsigned r = (unsigned)rank_g[(c << 12) + p];
    rankS[tid] = (unsigned short)r;
    const unsigned selfw = (r << 12) | (unsigned)p;      // global id
    st[2 * tid]     = selfw;                             // parw (root)
    st[2 * tid + 1] = selfw;                             // skipw (self)
    __syncthreads();

    // ---- insert 444 intra-strip edges (2 slots/thread), local indexing ----
    int xlA[2], pxA[2], x0A[2];
    unsigned ywA[2];
    unsigned act = 0;
#pragma unroll
    for (int k = 0; k < 2; ++k) {
        xlA[k] = 0; pxA[k] = -1; x0A[k] = 0; ywA[k] = 0;
        const int e = (k << 8) + tid;
        if (e < 444) {
            int xl, yl;
            if (e < 252) { const int lr = e / 63; xl = (lr << 6) + (e - lr * 63); yl = xl + 1; }
            else         { const int e2 = e - 252; xl = ((e2 >> 6) << 6) + (e2 & 63); yl = xl + 64; }
            unsigned rx = rankS[xl], ry = rankS[yl];
            if (rx > ry) { int t = xl; xl = yl; yl = t; unsigned tr = rx; rx = ry; ry = tr; }
            xlA[k]  = xl;
            x0A[k]  = xl;
            ywA[k]  = (ry << 12) | (unsigned)(base + yl);
            act    |= 1u << k;
        }
    }

    auto stepL = [&](int k, unsigned long long lv) {
        const int      xl = xlA[k];
        const unsigned xg = (unsigned)(base + xl);
        const unsigned yw = ywA[k];
        const unsigned ry = yw >> 12;
        const unsigned w  = (unsigned)lv;
        const unsigned sk = (unsigned)(lv >> 32);
        if (pxA[k] >= 0) { st[2 * pxA[k] + 1] = sk; pxA[k] = -1; }
        const unsigned s = sk & 0xFFFu;
        if (s != xg && (sk >> 12) <= ry) {                     // hint jump
            if (s == (yw & 0xFFFu)) { st[2 * x0A[k] + 1] = yw; act &= ~(1u << k); }
            else { pxA[k] = xl; xlA[k] = (int)(s & 255u); }
            return;
        }
        const unsigned pg = w & 0xFFFu, rp = w >> 12;
        if (pg == xg) {                                        // root: attach y
            if (atomicCAS(&st[2 * xl], w, yw) == w) {
                st[2 * xl + 1] = yw; st[2 * x0A[k] + 1] = yw;
                act &= ~(1u << k);
            }
        } else if (rp < ry) {                                  // climb
            if (s == xg) st[2 * xl + 1] = w;
            xlA[k] = (int)(pg & 255u);
        } else if (rp > ry) {                                  // splice
            if (atomicCAS(&st[2 * xl], w, yw) == w) {
                st[2 * xl + 1] = yw; st[2 * x0A[k] + 1] = yw;
                xlA[k] = (int)(yw & 255u); x0A[k] = xlA[k]; ywA[k] = w;
            }
        } else { st[2 * x0A[k] + 1] = yw; act &= ~(1u << k); } // p==y
    };

    while (act) {
        unsigned long long ld[2];
#pragma unroll
        for (int k = 0; k < 2; ++k)
            if (act & (1u << k))
                ld[k] = *((volatile unsigned long long*)&st[2 * xlA[k]]);
#pragma unroll
        for (int k = 0; k < 2; ++k)
            if (act & (1u << k)) stepL(k, ld[k]);
    }
    __syncthreads();

    word_g[2 * ((c << 12) + p)]     = st[2 * tid];
    word_g[2 * ((c << 12) + p) + 1] = st[2 * tid + 1];
}

// ---------------------------------------------------------------------------
// K2: cross-edge assembly (pipelined walks, wave=boundary) + canon + output.
// 3 blocks x 1024 threads.
// ---------------------------------------------------------------------------
__global__ __launch_bounds__(1024) void ct_assemble(const float* __restrict__ vw,
                                                    const int* __restrict__ rank_g,
                                                    const unsigned* __restrict__ word_g,
                                                    float* __restrict__ out) {
    __shared__ __align__(16) unsigned state[2 * N_PIX];  // 32 KB
    __shared__ float vals[N_PIX];                        // 16 KB
    const int c   = blockIdx.x;
    const int tid = threadIdx.x;

    for (int p = tid; p < N_PIX; p += 1024) {
        state[2 * p]     = word_g[2 * ((c << 12) + p)];
        state[2 * p + 1] = word_g[2 * ((c << 12) + p) + 1];
        vals[p]          = vw[p * CH + c];
    }
    __syncthreads();

    // ---- one cross edge per thread; WAVE = BOUNDARY (b = tid>>6) ----
    if (tid < 960) {
        const int b   = tid >> 6;               // boundary 0..14 (one wave each)
        const int col = tid & 63;
        int xg = (((b << 2) + 3) << 6) + col;   // row 4b+3
        int yg = xg + 64;                       // row 4b+4
        unsigned rx = (unsigned)rank_g[(c << 12) + xg];
        unsigned ry = (unsigned)rank_g[(c << 12) + yg];
        if (rx > ry) { int t = xg; xg = yg; yg = t; unsigned tr = rx; rx = ry; ry = tr; }

        int x = xg, x0 = xg, px = -1;
        unsigned yw = (ry << 12) | (unsigned)yg;
        volatile unsigned long long* vst = (volatile unsigned long long*)state;
        unsigned long long lv = vst[x];
        bool on = true;
        while (on) {
            const unsigned w   = (unsigned)lv;
            const unsigned sk  = (unsigned)(lv >> 32);
            const unsigned ryc = yw >> 12;
            const unsigned ylo = yw & 0xFFFu;
            const unsigned s   = sk & 0xFFFu;
            const unsigned p   = w & 0xFFFu;
            const unsigned rp  = w >> 12;

            const bool hjump = (s != (unsigned)x) && ((sk >> 12) <= ryc);
            const bool climb = !hjump && (p != (unsigned)x) && (rp < ryc);

            if (hjump | climb) {
                const int nx = (int)(hjump ? s : p);
                const bool term = hjump && (s == ylo);
                unsigned long long lvn = 0;
                if (!term) lvn = vst[nx];                    // issue early!
                // overlapped stores while lvn is in flight
                if (px >= 0) { state[2 * px + 1] = sk; px = -1; }
                if (term) { state[2 * x0 + 1] = yw; on = false; }
                else {
                    if (hjump) px = x;
                    else if (s == (unsigned)x) state[2 * x + 1] = w;  // memo
                    x = nx; lv = lvn;
                }
                continue;
            }

            // slow path: root attach / splice / p==y
            if (px >= 0) { state[2 * px + 1] = sk; px = -1; }
            if (p == (unsigned)x) {                          // root: attach y
                if (atomicCAS(&state[2 * x], w, yw) == w) {
                    state[2 * x + 1] = yw; state[2 * x0 + 1] = yw;
                    on = false;
                } else lv = vst[x];
            } else if (rp > ryc) {                           // splice
                if (atomicCAS(&state[2 * x], w, yw) == w) {
                    state[2 * x + 1] = yw; state[2 * x0 + 1] = yw;
                    x = (int)ylo; x0 = x; yw = w;
                }
                lv = vst[x];
            } else {                                         // rp==ryc => p==y
                state[2 * x0 + 1] = yw;
                on = false;
            }
        }
    }
    __syncthreads();

    // ---- canon (g[p] = climb-from-parent-while-f-equal) + output ----
    for (int p = tid; p < N_PIX; p += 1024) {
        int q = state[2 * p] & 0xFFF;
        const float fq = vals[q];
        for (;;) {
            const int qp = state[2 * q] & 0xFFF;
            if (qp == q) break;
            if (vals[qp] != fq) break;
            q = qp;
        }
        out[(c << 12) + p] = (float)q;
        out[CH * N_PIX + (c << 12) + p] = vals[p];
    }
}

extern "C" void kernel_launch(void* const* d_in, const int* in_sizes, int n_in,
                              void* d_out, int out_size, void* d_ws, size_t ws_size,
                              hipStream_t stream) {
    const float* vw = (const float*)d_in[0];
    float* out = (float*)d_out;

    int*      rank_g = (int*)d_ws;                        // 3*4096 ints
    unsigned* word_g = (unsigned*)(rank_g + CH * N_PIX);  // 2*3*4096 uints

    hipMemsetAsync(rank_g, 0, CH * N_PIX * sizeof(int), stream);
    ct_rank    <<<768, 256, 0, stream>>>(vw, rank_g);
    ct_build   <<<48, 256, 0, stream>>>(rank_g, word_g);
    ct_assemble<<<CH, 1024, 0, stream>>>(vw, rank_g, word_g, out);
}